// Round 1
// baseline (496.965 us; speedup 1.0000x reference)
//
#include <hip/hip_runtime.h>

// EdgeFeature: out[b,n,k,:] = concat(central(64), neighbor(64), rel(64), ||rel||^2(1))
// B=4 N=8192 C=64 K=20  -> 655360 edges, row = 193 floats.

typedef float f4v __attribute__((ext_vector_type(4)));

#define BLOCK 256
#define EPB   16          // edges per block
#define ROW   193         // 3*64 + 1 floats per edge

constexpr int Bc = 4, Nc = 8192, Kc = 20;
constexpr int NK = Nc * Kc;                 // 163840
constexpr int TOTAL_EDGES = Bc * NK;        // 655360
constexpr int BLK_FLOATS = EPB * ROW;       // 3088 (divisible by 4 -> aligned f4)
constexpr int BLK_F4 = BLK_FLOATS / 4;      // 772

__global__ __launch_bounds__(BLOCK)
void edge_feature_kernel(const float* __restrict__ pc,
                         const int* __restrict__ nn_idx,
                         float* __restrict__ out)
{
    __shared__ float lds[BLK_FLOATS];

    const int tid     = threadIdx.x;
    const int e_local = tid >> 4;        // 0..15: edge within block
    const int lg      = tid & 15;        // 0..15: 4-channel group within edge
    const int e       = blockIdx.x * EPB + e_local;   // global edge id

    // decode e -> (b, n); k not needed (nn_idx is flat-indexed by e)
    const int b   = e / NK;              // const divisor -> magic mul
    const int rem = e - b * NK;
    const int n   = rem / Kc;

    const int idx = nn_idx[e];

    const f4v* pc4 = (const f4v*)pc;     // pc rows: 64 floats = 16 f4, 256B aligned
    f4v cen = pc4[(b * Nc + n)   * 16 + lg];
    f4v nbr = pc4[(b * Nc + idx) * 16 + lg];
    f4v rel = nbr - cen;

    float part = rel.x * rel.x + rel.y * rel.y + rel.z * rel.z + rel.w * rel.w;
    // reduce squared distance across the 16 lanes of this edge
    part += __shfl_xor(part, 1, 16);
    part += __shfl_xor(part, 2, 16);
    part += __shfl_xor(part, 4, 16);
    part += __shfl_xor(part, 8, 16);

    float* row = &lds[e_local * ROW];
    const int c0 = lg * 4;
    row[c0 + 0]       = cen.x; row[c0 + 1]       = cen.y;
    row[c0 + 2]       = cen.z; row[c0 + 3]       = cen.w;
    row[64 + c0 + 0]  = nbr.x; row[64 + c0 + 1]  = nbr.y;
    row[64 + c0 + 2]  = nbr.z; row[64 + c0 + 3]  = nbr.w;
    row[128 + c0 + 0] = rel.x; row[128 + c0 + 1] = rel.y;
    row[128 + c0 + 2] = rel.z; row[128 + c0 + 3] = rel.w;
    if (lg == 0) row[192] = part;

    __syncthreads();

    // block's output window is contiguous & 16B-aligned: blast it out as f4
    const f4v* lds4 = (const f4v*)lds;
    f4v* out4 = (f4v*)(out + (size_t)blockIdx.x * BLK_FLOATS);
    #pragma unroll
    for (int i = tid; i < BLK_F4; i += BLOCK) {
        __builtin_nontemporal_store(lds4[i], &out4[i]);
    }
}

extern "C" void kernel_launch(void* const* d_in, const int* in_sizes, int n_in,
                              void* d_out, int out_size, void* d_ws, size_t ws_size,
                              hipStream_t stream)
{
    const float* pc     = (const float*)d_in[0];
    const int*   nn_idx = (const int*)d_in[1];
    float*       out    = (float*)d_out;

    const int grid = TOTAL_EDGES / EPB;   // 40960 blocks
    edge_feature_kernel<<<grid, BLOCK, 0, stream>>>(pc, nn_idx, out);
}